// Round 1
// baseline (51.499 us; speedup 1.0000x reference)
//
#include <hip/hip_runtime.h>

typedef __attribute__((ext_vector_type(8)))  __bf16 bf16x8;
typedef __attribute__((ext_vector_type(4)))  __bf16 bf16x4;
typedef __attribute__((ext_vector_type(16))) float  f32x16;
typedef __attribute__((ext_vector_type(4)))  float  f32x4;

#define B_    16
#define N_    2048
#define D_    64
#define QBLK  128      // q rows per block (4 waves x 32)
#define KVBLK 64
#define NT    (N_ / KVBLK)   // 32 tiles

static __device__ __forceinline__ float fast_exp2(float x) {
#if __has_builtin(__builtin_amdgcn_exp2f)
    return __builtin_amdgcn_exp2f(x);
#else
    return __expf(x * 0.6931471805599453f);
#endif
}

__global__ __launch_bounds__(256, 1)
void attn_fwd(const float* __restrict__ Qp, const float* __restrict__ Kp,
              const float* __restrict__ Vp, float* __restrict__ Op)
{
    __shared__ uint4 smem_u4[2048];            // 32 KiB: K dbuf 2x8K, Vt dbuf 2x8K
    char* smem = (char*)smem_u4;

    const int tid  = threadIdx.x;
    const int lane = tid & 63;
    const int w    = tid >> 6;                 // wave 0..3
    const int h    = lane >> 5;                // half 0/1
    const int qcol = lane & 31;                // q within wave tile / d row within 32-block

    const int bx    = blockIdx.x;
    const int batch = ((bx & 7) << 1) | (bx >> 7);   // XCD-local batches
    const int qtile = (bx >> 3) & 15;
    const int q0w   = qtile * QBLK + w * 32;

    const float SL2E = 0.18033688011112042f;   // (1/sqrt(64)) * log2(e)
    const size_t bboff = (size_t)batch * (N_ * D_);

    // ---------------- Q fragments (held in registers for all tiles) ---------
    const float* qrow = Qp + bboff + (size_t)(q0w + qcol) * D_ + h * 8;
    bf16x8 qf[4];
#pragma unroll
    for (int m = 0; m < 4; ++m) {
        f32x4 a = *reinterpret_cast<const f32x4*>(qrow + m * 16);
        f32x4 b = *reinterpret_cast<const f32x4*>(qrow + m * 16 + 4);
#pragma unroll
        for (int j = 0; j < 4; ++j) { qf[m][j] = (__bf16)a[j]; qf[m][4 + j] = (__bf16)b[j]; }
    }

    // ---------------- staging (global -> reg -> LDS) ------------------------
    const int krow = tid >> 2,  kcol = (tid & 3) * 16;   // K: 4 thr/row, 16 floats each
    const int vrow = tid & 63,  vcol = (tid >> 6) * 16;  // V: thread row, 16 d each
    const float* ksrc0 = Kp + bboff + (size_t)krow * D_ + kcol;
    const float* vsrc0 = Vp + bboff + (size_t)vrow * D_ + vcol;

    f32x4 kr[4], vr[4];
    auto load_tile = [&](int t) {
        const float* ks = ksrc0 + (size_t)t * KVBLK * D_;
        const float* vs = vsrc0 + (size_t)t * KVBLK * D_;
#pragma unroll
        for (int i = 0; i < 4; ++i) kr[i] = *reinterpret_cast<const f32x4*>(ks + 4 * i);
#pragma unroll
        for (int i = 0; i < 4; ++i) vr[i] = *reinterpret_cast<const f32x4*>(vs + 4 * i);
    };

    auto write_tile = [&](int b) {
        char* kb = smem + b * 8192;
        char* vb = smem + 16384 + b * 8192;
        // K: row-major [64][64] bf16, XOR-swizzled (row&7)<<4
        const int xr = (krow & 7) << 4;
        bf16x8 w0, w1;
#pragma unroll
        for (int j = 0; j < 4; ++j) {
            w0[j] = (__bf16)kr[0][j];  w0[4 + j] = (__bf16)kr[1][j];
            w1[j] = (__bf16)kr[2][j];  w1[4 + j] = (__bf16)kr[3][j];
        }
        *reinterpret_cast<bf16x8*>(kb + krow * 128 + ((kcol * 2)      ^ xr)) = w0;
        *reinterpret_cast<bf16x8*>(kb + krow * 128 + ((kcol * 2 + 16) ^ xr)) = w1;
        // V transposed: Vt[d][kv] bf16, XOR-swizzled (row&15)<<3 ; writes conflict-free
#pragma unroll 16
        for (int i = 0; i < 16; ++i) {
            const int d = vcol + i;
            *reinterpret_cast<__bf16*>(vb + d * 128 + ((vrow * 2) ^ ((d & 15) << 3))) =
                (__bf16)vr[i >> 2][i & 3];
        }
    };

    // ---------------- accumulators / softmax state --------------------------
    f32x16 o0, o1;
#pragma unroll
    for (int i = 0; i < 16; ++i) { o0[i] = 0.f; o1[i] = 0.f; }
    float m_run = -1e30f, l_run = 0.f;

    const int kx = (qcol & 7) << 4;            // K-read swizzle for this lane's row

    load_tile(0);
    write_tile(0);
    __syncthreads();

    for (int t = 0; t < NT; ++t) {
        const int cur = t & 1;
        if (t + 1 < NT) load_tile(t + 1);      // T14: issue next-tile loads early

        const char* kb = smem + cur * 8192;
        const char* vb = smem + 16384 + cur * 8192;

        // ---- QK^T : S^T[kv][q] = mfma(A=K, B=Q^T) ----
        f32x16 s0, s1;
#pragma unroll
        for (int i = 0; i < 16; ++i) { s0[i] = 0.f; s1[i] = 0.f; }
#pragma unroll
        for (int m = 0; m < 4; ++m) {
            const int col = m * 32 + h * 16;
            bf16x8 k0 = *reinterpret_cast<const bf16x8*>(kb + qcol * 128        + (col ^ kx));
            bf16x8 k1 = *reinterpret_cast<const bf16x8*>(kb + (32 + qcol) * 128 + (col ^ kx));
            s0 = __builtin_amdgcn_mfma_f32_32x32x16_bf16(k0, qf[m], s0, 0, 0, 0);
            s1 = __builtin_amdgcn_mfma_f32_32x32x16_bf16(k1, qf[m], s1, 0, 0, 0);
        }

        // ---- online softmax (q = lane&31; this lane owns its h-half of kv) ----
        float tmax = s0[0];
#pragma unroll
        for (int i = 1; i < 16; ++i) tmax = fmaxf(tmax, s0[i]);
#pragma unroll
        for (int i = 0; i < 16; ++i) tmax = fmaxf(tmax, s1[i]);
        tmax = fmaxf(tmax, __shfl_xor(tmax, 32));

        if (!__all(tmax <= m_run + 16.0f)) {   // T13 defer-max, THR=16 raw => p <= 7.4
            const float mnew  = fmaxf(m_run, tmax);
            const float alpha = fast_exp2((m_run - mnew) * SL2E);
            l_run *= alpha;
#pragma unroll
            for (int i = 0; i < 16; ++i) { o0[i] *= alpha; o1[i] *= alpha; }
            m_run = mnew;
        }

        const float nmk = -m_run * SL2E;
        float psum = 0.f;
        bf16x8 pf0a, pf0b, pf1a, pf1b;
#pragma unroll
        for (int i = 0; i < 8; ++i) {
            float p = fast_exp2(fmaf(s0[i], SL2E, nmk));
            psum += p; pf0a[i] = (__bf16)p;
        }
#pragma unroll
        for (int i = 0; i < 8; ++i) {
            float p = fast_exp2(fmaf(s0[8 + i], SL2E, nmk));
            psum += p; pf0b[i] = (__bf16)p;
        }
#pragma unroll
        for (int i = 0; i < 8; ++i) {
            float p = fast_exp2(fmaf(s1[i], SL2E, nmk));
            psum += p; pf1a[i] = (__bf16)p;
        }
#pragma unroll
        for (int i = 0; i < 8; ++i) {
            float p = fast_exp2(fmaf(s1[8 + i], SL2E, nmk));
            psum += p; pf1b[i] = (__bf16)p;
        }
        l_run += psum;

        // ---- PV : O^T[d][q] += mfma(A=Vt, B=P) ----
#pragma unroll
        for (int db = 0; db < 2; ++db) {
            const int drow = db * 32 + qcol;
            const char* vrowp = vb + drow * 128;
            const int vxx = (drow & 15) << 3;
            f32x16& oo = db ? o1 : o0;
#pragma unroll
            for (int kvb = 0; kvb < 2; ++kvb) {
#pragma unroll
                for (int sub = 0; sub < 2; ++sub) {
                    const int cb = kvb * 64 + sub * 32 + h * 8;
                    bf16x4 v0 = *reinterpret_cast<const bf16x4*>(vrowp + ((cb)      ^ vxx));
                    bf16x4 v1 = *reinterpret_cast<const bf16x4*>(vrowp + ((cb + 16) ^ vxx));
                    bf16x8 vf;
#pragma unroll
                    for (int j = 0; j < 4; ++j) { vf[j] = v0[j]; vf[4 + j] = v1[j]; }
                    const bf16x8 pa = (kvb == 0) ? (sub == 0 ? pf0a : pf0b)
                                                 : (sub == 0 ? pf1a : pf1b);
                    oo = __builtin_amdgcn_mfma_f32_32x32x16_bf16(vf, pa, oo, 0, 0, 0);
                }
            }
        }

        if (t + 1 < NT) write_tile((t + 1) & 1);  // other buffer: no race with readers
        __syncthreads();
    }

    // ---------------- epilogue: out[q][d] = O^T[d][q] / l ----------------
    const float lt  = l_run + __shfl_xor(l_run, 32);
    const float inv = 1.0f / lt;
    float* orow = Op + bboff + (size_t)(q0w + qcol) * D_;
#pragma unroll
    for (int db = 0; db < 2; ++db) {
        const f32x16& oo = db ? o1 : o0;
#pragma unroll
        for (int g = 0; g < 4; ++g) {
            f32x4 v;
#pragma unroll
            for (int r = 0; r < 4; ++r) v[r] = oo[4 * g + r] * inv;
            *reinterpret_cast<f32x4*>(orow + db * 32 + h * 4 + g * 8) = v;
        }
    }
}

extern "C" void kernel_launch(void* const* d_in, const int* in_sizes, int n_in,
                              void* d_out, int out_size, void* d_ws, size_t ws_size,
                              hipStream_t stream) {
    const float* Q = (const float*)d_in[0];
    const float* K = (const float*)d_in[1];
    const float* V = (const float*)d_in[2];
    float* O = (float*)d_out;
    dim3 grid(256), block(256);
    hipLaunchKernelGGL(attn_fwd, grid, block, 0, stream, Q, K, V, O);
}

// Round 2
// 43.689 us; speedup vs baseline: 1.1788x; 1.1788x over previous
//
#include <hip/hip_runtime.h>

typedef __attribute__((ext_vector_type(8)))  __bf16 bf16x8;
typedef __attribute__((ext_vector_type(4)))  __bf16 bf16x4;
typedef __attribute__((ext_vector_type(16))) float  f32x16;
typedef __attribute__((ext_vector_type(4)))  float  f32x4;

#define B_    16
#define N_    2048
#define D_    64
#define QBLK  128            // q rows per block (4 q-waves x 32)
#define KVBLK 64
#define NT    (N_ / KVBLK)   // 32 tiles
#define NG    2              // KV split groups per block
#define TPG   (NT / NG)      // 16 tiles per group

static __device__ __forceinline__ float fast_exp2(float x) {
#if __has_builtin(__builtin_amdgcn_exp2f)
    return __builtin_amdgcn_exp2f(x);
#else
    return __expf(x * 0.6931471805599453f);
#endif
}

__global__ __launch_bounds__(512, 2)
void attn_fwd(const float* __restrict__ Qp, const float* __restrict__ Kp,
              const float* __restrict__ Vp, float* __restrict__ Op)
{
    __shared__ uint4 smem_u4[4096];            // 64 KiB: per group 32K (K dbuf 16K + Vt dbuf 16K)
    char* smem = (char*)smem_u4;

    const int tid  = threadIdx.x;
    const int g    = tid >> 8;                 // KV group 0/1
    const int tg   = tid & 255;                // tid within group
    const int lane = tid & 63;
    const int w    = tg >> 6;                  // q-wave 0..3 within group
    const int h    = lane >> 5;                // half 0/1
    const int qcol = lane & 31;

    const int bx    = blockIdx.x;
    const int batch = ((bx & 7) << 1) | (bx >> 7);   // XCD-local batches
    const int qtile = (bx >> 3) & 15;
    const int q0w   = qtile * QBLK + w * 32;

    const float SL2E = 0.18033688011112042f;   // (1/sqrt(64)) * log2(e)
    const size_t bboff = (size_t)batch * (N_ * D_);

    char* gbase = smem + g * 32768;            // this group's staging area

    // ---------------- Q fragments (registers, reused across all tiles) ------
    const float* qrow = Qp + bboff + (size_t)(q0w + qcol) * D_ + h * 8;
    bf16x8 qf[4];
#pragma unroll
    for (int m = 0; m < 4; ++m) {
        f32x4 a = *reinterpret_cast<const f32x4*>(qrow + m * 16);
        f32x4 b = *reinterpret_cast<const f32x4*>(qrow + m * 16 + 4);
#pragma unroll
        for (int j = 0; j < 4; ++j) { qf[m][j] = (__bf16)a[j]; qf[m][4 + j] = (__bf16)b[j]; }
    }

    // ---------------- staging (global -> reg -> LDS), per group -------------
    const int krow = tg >> 2,  kcol = (tg & 3) * 16;   // K: 4 thr/row, 16 floats each
    const int vrow = tg & 63,  vcol = (tg >> 6) * 16;  // V: thread row, 16 d each
    const float* ksrc0 = Kp + bboff + (size_t)krow * D_ + kcol;
    const float* vsrc0 = Vp + bboff + (size_t)vrow * D_ + vcol;

    f32x4 kr[4], vr[4];
    auto load_tile = [&](int t) {              // t = global tile index
        const float* ks = ksrc0 + (size_t)t * KVBLK * D_;
        const float* vs = vsrc0 + (size_t)t * KVBLK * D_;
#pragma unroll
        for (int i = 0; i < 4; ++i) kr[i] = *reinterpret_cast<const f32x4*>(ks + 4 * i);
#pragma unroll
        for (int i = 0; i < 4; ++i) vr[i] = *reinterpret_cast<const f32x4*>(vs + 4 * i);
    };

    auto write_tile = [&](int b) {
        char* kb = gbase + b * 8192;
        char* vb = gbase + 16384 + b * 8192;
        // K: row-major [64][64] bf16, XOR-swizzled (row&7)<<4
        const int xr = (krow & 7) << 4;
        bf16x8 w0, w1;
#pragma unroll
        for (int j = 0; j < 4; ++j) {
            w0[j] = (__bf16)kr[0][j];  w0[4 + j] = (__bf16)kr[1][j];
            w1[j] = (__bf16)kr[2][j];  w1[4 + j] = (__bf16)kr[3][j];
        }
        *reinterpret_cast<bf16x8*>(kb + krow * 128 + ((kcol * 2)      ^ xr)) = w0;
        *reinterpret_cast<bf16x8*>(kb + krow * 128 + ((kcol * 2 + 16) ^ xr)) = w1;
        // V transposed: Vt[d][kv] bf16, XOR-swizzled (d&15)<<3
#pragma unroll 16
        for (int i = 0; i < 16; ++i) {
            const int d = vcol + i;
            *reinterpret_cast<__bf16*>(vb + d * 128 + ((vrow * 2) ^ ((d & 15) << 3))) =
                (__bf16)vr[i >> 2][i & 3];
        }
    };

    // ---------------- accumulators / softmax state --------------------------
    f32x16 o0, o1;
#pragma unroll
    for (int i = 0; i < 16; ++i) { o0[i] = 0.f; o1[i] = 0.f; }
    float m_run = -1e30f, l_run = 0.f;

    const int kx = (qcol & 7) << 4;            // K-read swizzle for this lane's row

    load_tile(g);
    write_tile(0);
    __syncthreads();

    for (int it = 0; it < TPG; ++it) {
        const int cur = it & 1;
        if (it + 1 < TPG) load_tile(NG * (it + 1) + g);  // issue next-tile loads early

        const char* kb = gbase + cur * 8192;
        const char* vb = gbase + 16384 + cur * 8192;

        // ---- QK^T : S^T[kv][q] = mfma(A=K, B=Q^T) ----
        f32x16 s0, s1;
#pragma unroll
        for (int i = 0; i < 16; ++i) { s0[i] = 0.f; s1[i] = 0.f; }
        __builtin_amdgcn_s_setprio(1);
#pragma unroll
        for (int m = 0; m < 4; ++m) {
            const int col = m * 32 + h * 16;
            bf16x8 k0 = *reinterpret_cast<const bf16x8*>(kb + qcol * 128        + (col ^ kx));
            bf16x8 k1 = *reinterpret_cast<const bf16x8*>(kb + (32 + qcol) * 128 + (col ^ kx));
            s0 = __builtin_amdgcn_mfma_f32_32x32x16_bf16(k0, qf[m], s0, 0, 0, 0);
            s1 = __builtin_amdgcn_mfma_f32_32x32x16_bf16(k1, qf[m], s1, 0, 0, 0);
        }
        __builtin_amdgcn_s_setprio(0);

        // ---- online softmax (q = lane&31) ----
        float tmax = s0[0];
#pragma unroll
        for (int i = 1; i < 16; ++i) tmax = fmaxf(tmax, s0[i]);
#pragma unroll
        for (int i = 0; i < 16; ++i) tmax = fmaxf(tmax, s1[i]);
        tmax = fmaxf(tmax, __shfl_xor(tmax, 32));

        if (!__all(tmax <= m_run + 16.0f)) {   // defer-max, THR=16 raw => p <= 7.4
            const float mnew  = fmaxf(m_run, tmax);
            const float alpha = fast_exp2((m_run - mnew) * SL2E);
            l_run *= alpha;
#pragma unroll
            for (int i = 0; i < 16; ++i) { o0[i] *= alpha; o1[i] *= alpha; }
            m_run = mnew;
        }

        const float nmk = -m_run * SL2E;
        float psum = 0.f;
        bf16x8 pf0a, pf0b, pf1a, pf1b;
#pragma unroll
        for (int i = 0; i < 8; ++i) {
            float p = fast_exp2(fmaf(s0[i], SL2E, nmk));
            psum += p; pf0a[i] = (__bf16)p;
        }
#pragma unroll
        for (int i = 0; i < 8; ++i) {
            float p = fast_exp2(fmaf(s0[8 + i], SL2E, nmk));
            psum += p; pf0b[i] = (__bf16)p;
        }
#pragma unroll
        for (int i = 0; i < 8; ++i) {
            float p = fast_exp2(fmaf(s1[i], SL2E, nmk));
            psum += p; pf1a[i] = (__bf16)p;
        }
#pragma unroll
        for (int i = 0; i < 8; ++i) {
            float p = fast_exp2(fmaf(s1[8 + i], SL2E, nmk));
            psum += p; pf1b[i] = (__bf16)p;
        }
        l_run += psum;

        // ---- PV : O^T[d][q] += mfma(A=Vt, B=P) ----
        __builtin_amdgcn_s_setprio(1);
#pragma unroll
        for (int db = 0; db < 2; ++db) {
            const int drow = db * 32 + qcol;
            const char* vrowp = vb + drow * 128;
            const int vxx = (drow & 15) << 3;
            f32x16& oo = db ? o1 : o0;
#pragma unroll
            for (int kvb = 0; kvb < 2; ++kvb) {
#pragma unroll
                for (int sub = 0; sub < 2; ++sub) {
                    const int cb = kvb * 64 + sub * 32 + h * 8;
                    bf16x4 v0 = *reinterpret_cast<const bf16x4*>(vrowp + ((cb)      ^ vxx));
                    bf16x4 v1 = *reinterpret_cast<const bf16x4*>(vrowp + ((cb + 16) ^ vxx));
                    bf16x8 vf;
#pragma unroll
                    for (int j = 0; j < 4; ++j) { vf[j] = v0[j]; vf[4 + j] = v1[j]; }
                    const bf16x8 pa = (kvb == 0) ? (sub == 0 ? pf0a : pf0b)
                                                 : (sub == 0 ? pf1a : pf1b);
                    oo = __builtin_amdgcn_mfma_f32_32x32x16_bf16(vf, pa, oo, 0, 0, 0);
                }
            }
        }
        __builtin_amdgcn_s_setprio(0);

        if (it + 1 < TPG) write_tile((it + 1) & 1);
        __syncthreads();
    }

    // ---------------- cross-group combine through LDS -----------------------
    const float lt = l_run + __shfl_xor(l_run, 32);   // full l for this group's kv set
    float* combO = (float*)smem;                      // A:[0,16K) g0's o1; B:[16K,32K) g1's o0
    float* ml    = (float*)(smem + 32768);            // ml0: [0,512) floats; ml1: [512,1024)
    const int slot = w * 64 + lane;                   // 0..255

    {
        float* dst = combO + (g ? 4096 : 0) + slot * 16;
        const f32x16& give = g ? o0 : o1;             // the half the OTHER group outputs
#pragma unroll
        for (int i = 0; i < 16; ++i) dst[i] = give[i];
        ml[g * 512 + slot * 2]     = m_run;
        ml[g * 512 + slot * 2 + 1] = lt;
    }
    __syncthreads();

    const float m_o = ml[(1 - g) * 512 + slot * 2];
    const float l_o = ml[(1 - g) * 512 + slot * 2 + 1];
    const f32x4* src = (const f32x4*)(combO + (g ? 0 : 4096) + slot * 16);
    const f32x16& mine = g ? o1 : o0;

    const float mm   = fmaxf(m_run, m_o);
    const float aown = fast_exp2((m_run - mm) * SL2E);
    const float aoth = fast_exp2((m_o  - mm) * SL2E);
    const float inv  = 1.0f / (aown * lt + aoth * l_o);

    float* orow = Op + bboff + (size_t)(q0w + qcol) * D_ + g * 32;
#pragma unroll
    for (int gg = 0; gg < 4; ++gg) {
        f32x4 v;
#pragma unroll
        for (int r = 0; r < 4; ++r)
            v[r] = (aown * mine[4 * gg + r] + aoth * src[gg][r]) * inv;
        *reinterpret_cast<f32x4*>(orow + h * 4 + gg * 8) = v;
    }
}

extern "C" void kernel_launch(void* const* d_in, const int* in_sizes, int n_in,
                              void* d_out, int out_size, void* d_ws, size_t ws_size,
                              hipStream_t stream) {
    const float* Q = (const float*)d_in[0];
    const float* K = (const float*)d_in[1];
    const float* V = (const float*)d_in[2];
    float* O = (float*)d_out;
    dim3 grid(256), block(512);
    hipLaunchKernelGGL(attn_fwd, grid, block, 0, stream, Q, K, V, O);
}